// Round 5
// baseline (94.661 us; speedup 1.0000x reference)
//
#include <hip/hip_runtime.h>
#include <math.h>

// ChamferDistanceL1: B=8, N=M=4096, fp32.
// R5: QPT=8 — R4 was co-limited by the CU-shared LDS pipe: 24 VALU instrs
// (48 SIMD-cyc) per ds_read_b128 (~12 cyc) x 4 SIMDs = LDS pipe 100% busy.
// Doubling queries/thread makes it 48 VALU instrs per read -> LDS pipe 50%,
// VALU becomes the sole limiter.
//  - groups of 8 lanes (NGRP=64, GRANGE=16); row pad +1 float4 (stride 17
//    = 68 dwords === 4 mod 32) -> 8 groups/wave hit disjoint bank quads.
//  - partial-min combine: in-wave __shfl_xor fmin over group bits (8,16,32),
//    then tiny 8x64 LDS array across waves; one atomicAdd(d_out)/block.
// Grid 1024 blocks = 4 blocks/CU = 32 waves/CU; LDS 19.5 KB; VGPR ~48 (<=64
// keeps 8 waves/SIMD).

#define BLK 512
#define QPB 64       // queries per block
#define NGRP 64      // groups of 8 lanes; group g scans 1/64 of each slice
#define QPT 8        // queries per thread (8 lanes * 8 = 64 = QPB)
#define SLICE 1024   // db points staged in LDS per slice
#define GRANGE (SLICE / NGRP)  // 16 db points per group per slice

__global__ __launch_bounds__(BLK) void chamfer_fused_kernel(
    const float* __restrict__ x, const float* __restrict__ y,
    float* __restrict__ out, int N, int M, float sx, float sy) {
  __shared__ float4 sdb[NGRP][GRANGE + 1];  // 64*17*16 = 17408 B, padded
  __shared__ float pmin[8][QPB];            // per-wave partials, 2 KB

  const int dir = blockIdx.z;  // 0: q=x db=y, 1: q=y db=x
  const int b = blockIdx.y;
  const float* __restrict__ q  = dir ? y : x;
  const float* __restrict__ db = dir ? x : y;
  const int Nq  = dir ? M : N;
  const int Ndb = dir ? N : M;
  const float scale = dir ? sy : sx;

  const float* __restrict__ qb  = q  + (size_t)b * Nq  * 3;
  const float* __restrict__ dbb = db + (size_t)b * Ndb * 3;

  const int t = threadIdx.x;
  const int g = t >> 3;   // group id   [0,64)
  const int u = t & 7;    // lane-in-group

  // Load this thread's 8 queries into registers.
  const int q0 = blockIdx.x * QPB;
  float qx[QPT], qy[QPT], qz[QPT], dmin[QPT];
#pragma unroll
  for (int k = 0; k < QPT; ++k) {
    int qi = q0 + u + 8 * k;
    if (qi >= Nq) qi = Nq - 1;
    qx[k] = qb[3 * qi + 0];
    qy[k] = qb[3 * qi + 1];
    qz[k] = qb[3 * qi + 2];
    dmin[k] = 3.0e38f;
  }

  // Scan the full DB in LDS slices; mins accumulate across slices.
  for (int s0 = 0; s0 < Ndb; s0 += SLICE) {
    const int send = min(SLICE, Ndb - s0);
    for (int p = t; p < send; p += BLK) {
      const int j = s0 + p;
      sdb[p >> 4][p & 15] =
          make_float4(dbb[3 * j + 0], dbb[3 * j + 1], dbb[3 * j + 2], 0.0f);
    }
    __syncthreads();

    const int lim = min(GRANGE, send - g * GRANGE);
#pragma unroll 4
    for (int tt = 0; tt < lim; ++tt) {
      const float4 p = sdb[g][tt];
#pragma unroll
      for (int k = 0; k < QPT; ++k) {
        const float d =
            fabsf(qx[k] - p.x) + fabsf(qy[k] - p.y) + fabsf(qz[k] - p.z);
        dmin[k] = fminf(dmin[k], d);
      }
    }
    __syncthreads();
  }

  // In-wave: fmin across the 8 groups of this wave (lanes differing in
  // bits 3..5 hold the same queries). After this, lanes with (l&63)<8 hold
  // the wave-final min for queries u + 8k.
#pragma unroll
  for (int k = 0; k < QPT; ++k) {
    float m = dmin[k];
    m = fminf(m, __shfl_xor(m, 8, 64));
    m = fminf(m, __shfl_xor(m, 16, 64));
    m = fminf(m, __shfl_xor(m, 32, 64));
    dmin[k] = m;
  }
  const int w = t >> 6;     // wave id [0,8)
  const int l = t & 63;     // lane id
  if (l < 8) {
#pragma unroll
    for (int k = 0; k < QPT; ++k) pmin[w][l + 8 * k] = dmin[k];
  }
  __syncthreads();

  // Cross-wave combine + sum + single atomicAdd.
  if (t < QPB) {  // first wave; t indexes the query within the block
    float m = pmin[0][t];
#pragma unroll
    for (int ww = 1; ww < 8; ++ww) m = fminf(m, pmin[ww][t]);
#pragma unroll
    for (int o = 32; o > 0; o >>= 1) m += __shfl_down(m, o, 64);
    if (t == 0) atomicAdd(out, m * scale);
  }
}

extern "C" void kernel_launch(void* const* d_in, const int* in_sizes, int n_in,
                              void* d_out, int out_size, void* d_ws, size_t ws_size,
                              hipStream_t stream) {
  const float* x = (const float*)d_in[0];
  const float* y = (const float*)d_in[1];
  const int B = 8;
  const int N = in_sizes[0] / (B * 3);
  const int M = in_sizes[1] / (B * 3);  // N == M == 4096 for this problem

  float* out = (float*)d_out;
  // Zero the scalar accumulator (d_out is poisoned before every launch).
  hipMemsetAsync(out, 0, sizeof(float), stream);

  dim3 blk(BLK);
  dim3 grd((N + QPB - 1) / QPB, B, 2);  // N == M: same x-extent both dirs
  chamfer_fused_kernel<<<grd, blk, 0, stream>>>(
      x, y, out, N, M, 1.0f / (float)(B * N), 1.0f / (float)(B * M));
}

// Round 6
// 87.502 us; speedup vs baseline: 1.0818x; 1.0818x over previous
//
#include <hip/hip_runtime.h>
#include <math.h>

// ChamferDistanceL1: B=8, N=M=4096, fp32.
// R6: R4 config (BLK=512, QPT=4, padded conflict-free LDS rows, 32 waves/CU)
// plus:
//  1) compile-time trip counts (template NDB_CT=4096): R5's inner bound
//     lim=min(GRANGE, send-g*GRANGE) was THREAD-VARYING (g per-lane) ->
//     divergent loop + no immediate-offset unroll. Now fully unrolled,
//     uniform, ds_read offsets are immediates.
//  2) paired points: fminf(dmin, fminf(d0,d1)) -> v_min3_f32 (11 instr per
//     2 pairs instead of 12).
//  3) no d_out memset, no atomics: blocks store pre-scaled partial sums to
//     d_ws; 1-block finalize kernel plain-stores d_out. Graph = 2 kernel
//     nodes, 0 memsets (tests whether R3-R5's ~48us total-vs-kernel gap was
//     caused by the memset+atomic structure; R2's 2-kernel graph had ~25us).

#define BLK 512
#define QPB 64       // queries per block
#define NGRP 32      // groups of 16 lanes; group g scans GRANGE pts/slice
#define QPT 4        // queries per thread (16 lanes * 4 = 64 = QPB)
#define SLICE 1024   // db points staged in LDS per slice
#define GRANGE (SLICE / NGRP)  // 32
#define NWAVE (BLK / 64)       // 8

template <int NDB_CT>
__global__ __launch_bounds__(BLK) void chamfer_partial_kernel(
    const float* __restrict__ x, const float* __restrict__ y,
    float* __restrict__ partial, int N, int M, float sx, float sy) {
  __shared__ float4 sdb[NGRP][GRANGE + 1];  // 32*33*16 B, pad: stride 132
                                            // dwords == 4 mod 32 -> the 4
                                            // groups/wave hit disjoint quads
  __shared__ float pmin[NWAVE][QPB];        // cross-wave partial mins, 2 KB

  const int dir = blockIdx.z;  // 0: q=x db=y, 1: q=y db=x
  const int b = blockIdx.y;
  const float* __restrict__ q  = dir ? y : x;
  const float* __restrict__ db = dir ? x : y;
  const int Nq  = dir ? M : N;
  const int Ndb = dir ? N : M;
  const float scale = dir ? sy : sx;

  const float* __restrict__ qb  = q  + (size_t)b * Nq  * 3;
  const float* __restrict__ dbb = db + (size_t)b * Ndb * 3;

  const int t = threadIdx.x;
  const int g = t >> 4;   // group id   [0,32)
  const int u = t & 15;   // lane-in-group

  const int q0 = blockIdx.x * QPB;
  float qx[QPT], qy[QPT], qz[QPT], dmin[QPT];
#pragma unroll
  for (int k = 0; k < QPT; ++k) {
    int qi = q0 + u + 16 * k;
    if (qi >= Nq) qi = Nq - 1;  // generic-path clamp; masked at reduce
    qx[k] = qb[3 * qi + 0];
    qy[k] = qb[3 * qi + 1];
    qz[k] = qb[3 * qi + 2];
    dmin[k] = 3.0e38f;
  }

  const int ndb = NDB_CT ? NDB_CT : Ndb;
  for (int s0 = 0; s0 < ndb; s0 += SLICE) {
    // ---- stage SLICE db points into LDS ----
    if (NDB_CT) {
#pragma unroll
      for (int r = 0; r < SLICE / BLK; ++r) {
        const int p = t + r * BLK;
        const int j = s0 + p;
        sdb[p >> 5][p & 31] =
            make_float4(dbb[3 * j + 0], dbb[3 * j + 1], dbb[3 * j + 2], 0.0f);
      }
    } else {
      const int send = min(SLICE, ndb - s0);
      for (int p = t; p < send; p += BLK) {
        const int j = s0 + p;
        sdb[p >> 5][p & 31] =
            make_float4(dbb[3 * j + 0], dbb[3 * j + 1], dbb[3 * j + 2], 0.0f);
      }
    }
    __syncthreads();

    // ---- scan this group's GRANGE points for all QPT queries ----
    if (NDB_CT) {
#pragma unroll
      for (int tt = 0; tt < GRANGE; tt += 2) {
        const float4 p0 = sdb[g][tt];
        const float4 p1 = sdb[g][tt + 1];
#pragma unroll
        for (int k = 0; k < QPT; ++k) {
          const float d0 =
              fabsf(qx[k] - p0.x) + fabsf(qy[k] - p0.y) + fabsf(qz[k] - p0.z);
          const float d1 =
              fabsf(qx[k] - p1.x) + fabsf(qy[k] - p1.y) + fabsf(qz[k] - p1.z);
          dmin[k] = fminf(dmin[k], fminf(d0, d1));  // v_min3_f32
        }
      }
    } else {
      const int send = min(SLICE, ndb - s0);
      const int base = g * GRANGE;
      const int lim = min(GRANGE, max(0, send - base));
      for (int tt = 0; tt < lim; ++tt) {
        const float4 p0 = sdb[g][tt];
#pragma unroll
        for (int k = 0; k < QPT; ++k) {
          const float d0 =
              fabsf(qx[k] - p0.x) + fabsf(qy[k] - p0.y) + fabsf(qz[k] - p0.z);
          dmin[k] = fminf(dmin[k], d0);
        }
      }
    }
    __syncthreads();
  }

  // ---- combine the 4 groups inside each wave (lane bits 4,5) ----
#pragma unroll
  for (int k = 0; k < QPT; ++k) {
    float m = dmin[k];
    m = fminf(m, __shfl_xor(m, 16, 64));
    m = fminf(m, __shfl_xor(m, 32, 64));
    dmin[k] = m;
  }
  const int w = t >> 6;  // wave id [0,8)
  const int l = t & 63;
  if (l < 16) {
#pragma unroll
    for (int k = 0; k < QPT; ++k) pmin[w][l + 16 * k] = dmin[k];
  }
  __syncthreads();

  // ---- cross-wave min, sum the 64 finals, store one pre-scaled partial ----
  if (t < QPB) {  // t = (u) + 16*k query index within block
    float m = pmin[0][t];
#pragma unroll
    for (int ww = 1; ww < NWAVE; ++ww) m = fminf(m, pmin[ww][t]);
    if (q0 + t >= Nq) m = 0.0f;  // mask padded queries (generic path)
#pragma unroll
    for (int o = 32; o > 0; o >>= 1) m += __shfl_down(m, o, 64);
    if (t == 0) {
      const int bid = (blockIdx.z * gridDim.y + blockIdx.y) * gridDim.x +
                      blockIdx.x;
      partial[bid] = m * scale;
    }
  }
}

__global__ __launch_bounds__(256) void chamfer_finalize_kernel(
    const float* __restrict__ part, float* __restrict__ out, int n) {
  float s = 0.0f;
  for (int i = threadIdx.x; i < n; i += 256) s += part[i];
#pragma unroll
  for (int o = 32; o > 0; o >>= 1) s += __shfl_down(s, o, 64);
  __shared__ float ws[4];
  const int w = threadIdx.x >> 6;
  if ((threadIdx.x & 63) == 0) ws[w] = s;
  __syncthreads();
  if (threadIdx.x == 0) out[0] = ws[0] + ws[1] + ws[2] + ws[3];
}

extern "C" void kernel_launch(void* const* d_in, const int* in_sizes, int n_in,
                              void* d_out, int out_size, void* d_ws, size_t ws_size,
                              hipStream_t stream) {
  const float* x = (const float*)d_in[0];
  const float* y = (const float*)d_in[1];
  const int B = 8;
  const int N = in_sizes[0] / (B * 3);
  const int M = in_sizes[1] / (B * 3);

  float* partial = (float*)d_ws;  // one float per block
  float* out = (float*)d_out;
  const float sx = 1.0f / (float)(B * N);
  const float sy = 1.0f / (float)(B * M);

  dim3 blk(BLK);
  if (N == 4096 && M == 4096) {
    dim3 grd(4096 / QPB, B, 2);
    chamfer_partial_kernel<4096><<<grd, blk, 0, stream>>>(
        x, y, partial, N, M, sx, sy);
    chamfer_finalize_kernel<<<1, 256, 0, stream>>>(
        partial, out, (int)(grd.x * grd.y * grd.z));
  } else {
    const int mx = (N > M) ? N : M;
    dim3 grd((mx + QPB - 1) / QPB, B, 2);
    chamfer_partial_kernel<0><<<grd, blk, 0, stream>>>(
        x, y, partial, N, M, sx, sy);
    chamfer_finalize_kernel<<<1, 256, 0, stream>>>(
        partial, out, (int)(grd.x * grd.y * grd.z));
  }
}